// Round 10
// baseline (221.474 us; speedup 1.0000x reference)
//
#include <hip/hip_runtime.h>
#include <hip/hip_bf16.h>
#include <stdint.h>
#include <stddef.h>

#define NB    64      // batch
#define NTOK  784
#define DIMC  256
#define NN2   4
#define NM    8
#define NHW   196
#define NWIN  32      // windows per batch
#define NROWS 2048    // NB*NWIN
#define NK    392
#define NKP   448     // K padded (bias at k=392, zeros after)
#define NBIG  38416   // HW*HW source cols
#define NIP   200     // i-stride within a j-row of E
#define STROW 39200   // used elements per window-row of E
#define STROW2 39232  // padded window-row stride
#define NPT   39424   // padded B rows (col') = 154*256
#define NTT   154     // N tiles of 256
#define PTS   232     // xvT i-stride

typedef __attribute__((ext_vector_type(4))) float f32x4;
typedef __attribute__((ext_vector_type(8))) short bf16x8;

static __device__ __forceinline__ float bf2f(unsigned short u) {
  union { unsigned int i; float f; } v; v.i = ((unsigned int)u) << 16; return v.f;
}
static __device__ __forceinline__ unsigned short f2bf(float f) {
  union { float f; unsigned int i; } v; v.f = f;
  unsigned int r = v.i + 0x7fffu + ((v.i >> 16) & 1u);  // RNE
  return (unsigned short)(r >> 16);
}

// ---------- kernel 1: compress (x@Wc+bc) + rearrange -> A bf16 [NROWS][NKP]
// K-pad: A[.,392] = 1.0 (bias lane), rest 0.
__global__ __launch_bounds__(256) void k_compress(
    const float* __restrict__ x, const float* __restrict__ Wc,
    const float* __restrict__ bc, unsigned short* __restrict__ Abf) {
  __shared__ float wcs[16 * 256];
  __shared__ float bcs[16];
  const int tid = threadIdx.x;
  const int b  = blockIdx.x / NN2;
  const int n2 = blockIdx.x % NN2;
  for (int idx = tid; idx < 4096; idx += 256) {
    int c = idx >> 4, md = idx & 15;
    wcs[md * 256 + c] = Wc[idx];
  }
  if (tid < 16) bcs[tid] = bc[tid];
  __syncthreads();
  if (tid < NHW) {
    const int h = tid / 7, wcol = tid % 7;
    const int t = h * 28 + n2 * 7 + wcol;
    const float* xp = x + ((size_t)b * NTOK + t) * DIMC;
    float acc[16];
    #pragma unroll
    for (int md = 0; md < 16; ++md) acc[md] = bcs[md];
    for (int c = 0; c < 256; c += 4) {
      const f32x4 xv = *(const f32x4*)(xp + c);
      #pragma unroll
      for (int md = 0; md < 16; ++md) {
        const f32x4 wv = *(const f32x4*)(wcs + md * 256 + c);
        acc[md] += xv[0]*wv[0] + xv[1]*wv[1] + xv[2]*wv[2] + xv[3]*wv[3];
      }
    }
    #pragma unroll
    for (int md = 0; md < 16; ++md) {
      const int m = md >> 1, d = md & 1;
      const int r = b * NWIN + n2 * NM + m;
      Abf[(size_t)r * NKP + tid * 2 + d] = f2bf(acc[md]);
    }
  }
  for (int e = tid; e < NM * (NKP - NK); e += 256) {
    const int m = e / (NKP - NK);
    const int k = NK + (e % (NKP - NK));
    const int r = b * NWIN + n2 * NM + m;
    Abf[(size_t)r * NKP + k] = (k == NK) ? (unsigned short)0x3F80 : 0;
  }
}

// ---------- kernel 2: Wg [NK][NBIG] f32 (+bg folded at k=392) -> Wgbt [NPT][NKP] bf16
__global__ __launch_bounds__(256) void k_wgt(
    const float* __restrict__ Wg, const float* __restrict__ bg,
    unsigned short* __restrict__ Wgbt) {
  __shared__ float tile[64][65];
  const int bid = blockIdx.x;
  const int n0 = (bid % 601) * 64;
  const int k0 = (bid / 601) * 64;
  const int tid = threadIdx.x;
  for (int idx = tid; idx < 4096; idx += 256) {
    const int kk = idx >> 6, nn = idx & 63;
    const int k = k0 + kk, n = n0 + nn;
    float v = 0.f;
    if (n < NBIG) {
      if (k < NK) v = Wg[(size_t)k * NBIG + n];
      else if (k == NK) v = bg[n];
    }
    tile[nn][kk] = v;
  }
  __syncthreads();
  for (int idx = tid; idx < 512; idx += 256) {
    const int nn = idx >> 3, gg = idx & 7;
    const int n = n0 + nn;
    if (n < NBIG) {
      const int i = n / NHW, j = n - (n / NHW) * NHW;
      const int np = j * NIP + i;
      unsigned short u8[8];
      #pragma unroll
      for (int e = 0; e < 8; ++e) u8[e] = f2bf(tile[nn][gg * 8 + e]);
      *(uint4*)&Wgbt[(size_t)np * NKP + k0 + gg * 8] = *(const uint4*)u8;
    }
  }
}

// ---------- kernel 2b: zero Wgbt pad rows (i in [196,200) and rows >= 39200)
__global__ __launch_bounds__(256) void k_zero(unsigned short* __restrict__ Wgbt) {
  const int bid = blockIdx.x;
  int np;
  if (bid < 784) { const int j = bid >> 2, i = 196 + (bid & 3); np = j * NIP + i; }
  else           { np = STROW + (bid - 784); }
  unsigned int* p = (unsigned int*)(Wgbt + (size_t)np * NKP);
  if (threadIdx.x < 224) p[threadIdx.x] = 0u;
}

// ---------- kernel 3: E[rc][STROW2] = exp(A @ Wgbt^T)   (bias folded into K)
// 256x256 block, 8 waves (wave 64x128), XOR-swizzled dbuf LDS,
// counted-vmcnt(8) raw-barrier pipeline (no per-tile drain).
__global__ __launch_bounds__(512, 2) void k_gemm(
    const unsigned short* __restrict__ A,    // chunk base [rc][NKP]
    const unsigned short* __restrict__ Bt,   // [NPT][NKP]
    unsigned short* __restrict__ E, int mtiles) {
  __shared__ __align__(128) short smem[65536];   // 128 KB: 2 x (A 32KB || B 32KB)
  const int tid = threadIdx.x;
  const int w = tid >> 6, lane = tid & 63;
  const int nwg = gridDim.x;
  const int q = nwg >> 3, rr = nwg & 7;
  const int xcd = blockIdx.x & 7, pos = blockIdx.x >> 3;
  const int wg = (xcd < rr ? xcd * (q + 1) : rr * (q + 1) + (xcd - rr) * q) + pos;
  const int nt = wg / mtiles, mt = wg % mtiles;
  const int m0 = mt * 256, n0 = nt * 256;
  const int lrow = lane >> 3, lgran = lane & 7;
  const int srcg = (lgran ^ lrow) * 8;          // pre-swizzled source granule

  // staging: wave w owns rows [w*64, (w+1)*64) of [A(256 rows) || B(256 rows)]
  const unsigned short* srow = (w < 4)
      ? A  + (size_t)(m0 + w * 64 + lrow) * NKP + srcg
      : Bt + (size_t)(n0 + (w - 4) * 64 + lrow) * NKP + srcg;
  const int dstb0 = ((w < 4) ? 0 : 32768) + (w & 3) * 8192;

  auto stage = [&](int kt, int buf) {
    #pragma unroll
    for (int is = 0; is < 8; ++is) {
      __builtin_amdgcn_global_load_lds(
          (const __attribute__((address_space(1))) void*)(srow + (size_t)is * 8 * NKP + kt),
          (__attribute__((address_space(3))) void*)((char*)smem + buf * 65536 + dstb0 + is * 1024),
          16, 0, 0);
    }
  };

  const int wm0 = (w >> 1) * 64;    // wave M offset (block-local)
  const int wn0 = (w & 1) * 128;    // wave N offset
  const int lq = lane >> 4, lx = lane & 7, cr = lane & 15;
  f32x4 acc[4][8] = {};

  stage(0, 0);
  #pragma unroll
  for (int t = 0; t < 7; ++t) {
    if (t < 6) {
      stage((t + 1) * 64, (t + 1) & 1);
      asm volatile("s_waitcnt vmcnt(8)" ::: "memory");
    } else {
      asm volatile("s_waitcnt vmcnt(0)" ::: "memory");
    }
    __builtin_amdgcn_s_barrier();
    asm volatile("" ::: "memory");
    const short* ab = smem + (t & 1) * 32768;
    const short* bb = ab + 16384;
    #pragma unroll
    for (int kk = 0; kk < 2; ++kk) {
      const int slot = ((kk * 4 + lq) ^ lx) * 8;
      bf16x8 af[4], bfr[8];
      #pragma unroll
      for (int mi = 0; mi < 4; ++mi)
        af[mi] = *(const bf16x8*)(ab + (wm0 + mi * 16 + cr) * 64 + slot);
      #pragma unroll
      for (int ni = 0; ni < 8; ++ni)
        bfr[ni] = *(const bf16x8*)(bb + (wn0 + ni * 16 + cr) * 64 + slot);
      #pragma unroll
      for (int mi = 0; mi < 4; ++mi)
        #pragma unroll
        for (int ni = 0; ni < 8; ++ni)
          acc[mi][ni] = __builtin_amdgcn_mfma_f32_16x16x32_bf16(af[mi], bfr[ni], acc[mi][ni], 0, 0, 0);
    }
    asm volatile("" ::: "memory");
    __builtin_amdgcn_s_barrier();
  }

  // epilogue: two 128-row half-passes: exp -> LDS (stride 264) -> coalesced 16B stores
  #pragma unroll
  for (int h = 0; h < 2; ++h) {
    if (h) {
      asm volatile("" ::: "memory");
      __builtin_amdgcn_s_barrier();
      asm volatile("" ::: "memory");
    }
    if ((w >> 2) == h) {
      #pragma unroll
      for (int mi = 0; mi < 4; ++mi)
        #pragma unroll
        for (int ni = 0; ni < 8; ++ni)
          #pragma unroll
          for (int e = 0; e < 4; ++e) {
            const int rl = wm0 - h * 128 + mi * 16 + lq * 4 + e;
            const int cl = wn0 + ni * 16 + cr;
            smem[rl * 264 + cl] = (short)f2bf(__expf(acc[mi][ni][e]));
          }
    }
    asm volatile("" ::: "memory");
    __builtin_amdgcn_s_barrier();
    asm volatile("" ::: "memory");
    for (int g = tid; g < 4096; g += 512) {
      const int rl = g >> 5, seg = g & 31;
      const int col0 = n0 + seg * 8;
      if (col0 < STROW2) {
        const uint4 v = *(const uint4*)&smem[rl * 264 + seg * 8];
        *(uint4*)&E[(size_t)(m0 + h * 128 + rl) * STROW2 + col0] = v;
      }
    }
  }
}

// ---------- kernel 4: mix. Window split across 2 blocks at jt granularity.
__global__ __launch_bounds__(512) void k_mix(
    const unsigned short* __restrict__ E, const float* __restrict__ x,
    float* __restrict__ out, int row0) {
  __shared__ unsigned short Elds[22528];     // up to 44 chunks * 64 granules * 8
  __shared__ unsigned short xvT[32 * PTS];   // [c][i] bf16
  const int tid = threadIdx.x, w = tid >> 6, lane = tid & 63;
  const int row = blockIdx.x >> 1, jh = blockIdx.x & 1;
  const int r = row0 + row;
  const int b = r >> 5, win = r & 31, n2 = win >> 3, m = win & 7;

  // phase 1: stream E half-row into LDS (linear), issue first
  const unsigned short* Eb = E + (size_t)row * STROW2;
  const int g0 = jh ? 2800 : 0;            // first 8-short granule of this half
  const int nch = jh ? 33 : 44;            // 64-granule chunks streamed
  for (int ch = w; ch < nch; ch += 8) {
    const int gr = g0 + ch * 64 + lane;
    if (gr < 4904)
      __builtin_amdgcn_global_load_lds(
          (const __attribute__((address_space(1))) void*)(Eb + (size_t)gr * 8),
          (__attribute__((address_space(3))) void*)((char*)Elds + ch * 1024), 16, 0, 0);
  }

  // phase 2: xvT[c][i] = x[b, t(i), m*32+c]; zero pads i in [196,232)
  for (int idx = tid; idx < 1568; idx += 512) {
    const int i = idx >> 3, c4 = (idx & 7) * 4;
    const int t = (i / 7) * 28 + n2 * 7 + (i % 7);
    const f32x4 v = *(const f32x4*)(x + ((size_t)b * NTOK + t) * DIMC + m * 32 + c4);
    xvT[(c4 + 0) * PTS + i] = f2bf(v[0]);
    xvT[(c4 + 1) * PTS + i] = f2bf(v[1]);
    xvT[(c4 + 2) * PTS + i] = f2bf(v[2]);
    xvT[(c4 + 3) * PTS + i] = f2bf(v[3]);
  }
  for (int idx = tid; idx < 32 * (PTS - NHW); idx += 512) {
    const int c = idx / (PTS - NHW), i = NHW + idx % (PTS - NHW);
    xvT[c * PTS + i] = 0;
  }
  __syncthreads();

  // hoist B-frags (channels) + ones-frags for the denominator
  bf16x8 bfr[2][7];
  #pragma unroll
  for (int ct = 0; ct < 2; ++ct)
    #pragma unroll
    for (int kk = 0; kk < 7; ++kk)
      bfr[ct][kk] = *(const bf16x8*)&xvT[(ct * 16 + (lane & 15)) * PTS + kk * 32 + (lane >> 4) * 8];
  const bool den = (lane & 15) == 0;
  bf16x8 oneA, oneB;
  #pragma unroll
  for (int e = 0; e < 8; ++e) {
    oneA[e] = den ? (short)0x3F80 : (short)0;
    const int i6 = 192 + (lane >> 4) * 8 + e;
    oneB[e] = (den && i6 < NHW) ? (short)0x3F80 : (short)0;
  }

  // phase 3: MFMA from LDS; wave w owns jt = jt0 + w
  const int jt0 = jh ? 7 : 0;
  const int jtend = jh ? 13 : 7;
  for (int jt = jt0 + w; jt < jtend; jt += 8) {
    const int jA = jt * 16 + (lane & 15);
    const int jAc = (jA < NHW) ? jA : NHW - 1;
    const unsigned short* rp = Elds + jAc * NIP - jh * 22400 + (lane >> 4) * 8;
    bf16x8 af[7];
    #pragma unroll
    for (int kk = 0; kk < 7; ++kk) af[kk] = *(const bf16x8*)(rp + kk * 32);
    f32x4 a0 = {0.f,0.f,0.f,0.f}, a1 = {0.f,0.f,0.f,0.f}, ad = {0.f,0.f,0.f,0.f};
    #pragma unroll
    for (int kk = 0; kk < 7; ++kk) {
      a0 = __builtin_amdgcn_mfma_f32_16x16x32_bf16(af[kk], bfr[0][kk], a0, 0, 0, 0);
      a1 = __builtin_amdgcn_mfma_f32_16x16x32_bf16(af[kk], bfr[1][kk], a1, 0, 0, 0);
      ad = __builtin_amdgcn_mfma_f32_16x16x32_bf16(af[kk], (kk < 6) ? oneA : oneB, ad, 0, 0, 0);
    }
    const int c = lane & 15;
    #pragma unroll
    for (int e = 0; e < 4; ++e) {
      const int j = jt * 16 + (lane >> 4) * 4 + e;
      const float dv = __shfl(ad[e], lane & 48);
      if (j < NHW) {
        const float inv = 1.f / dv;
        const int t2 = (j / 7) * 28 + n2 * 7 + (j % 7);
        float* op = out + ((size_t)b * NTOK + t2) * DIMC + m * 32;
        op[c] = a0[e] * inv;
        op[c + 16] = a1[e] * inv;
      }
    }
  }
}

extern "C" void kernel_launch(void* const* d_in, const int* in_sizes, int n_in,
                              void* d_out, int out_size, void* d_ws, size_t ws_size,
                              hipStream_t stream) {
  const float* x  = (const float*)d_in[0];
  const float* Wc = (const float*)d_in[1];
  const float* bc = (const float*)d_in[2];
  const float* Wg = (const float*)d_in[3];
  const float* bg = (const float*)d_in[4];
  float* out = (float*)d_out;

  char* ws = (char*)d_ws;
  const size_t wgbt_bytes = (size_t)NPT * NKP * 2;     // 35.3 MB
  const size_t a_bytes    = (size_t)NROWS * NKP * 2;   // 1.8 MB
  unsigned short* Wgbt = (unsigned short*)ws;
  unsigned short* Abf  = (unsigned short*)(ws + wgbt_bytes);
  unsigned short* E    = (unsigned short*)(ws + wgbt_bytes + a_bytes);
  const size_t fixed = wgbt_bytes + a_bytes;
  const size_t srow_bytes = (size_t)STROW2 * 2;        // 78.5 KB per window-row

  size_t avail = (ws_size > fixed) ? (ws_size - fixed) : 0;
  int rows_chunk = (int)(avail / srow_bytes);
  rows_chunk = (rows_chunk / 256) * 256;
  if (rows_chunk > NROWS) rows_chunk = NROWS;
  if (rows_chunk < 256)  rows_chunk = 256;

  hipLaunchKernelGGL(k_compress, dim3(NB * NN2), dim3(256), 0, stream, x, Wc, bc, Abf);
  hipLaunchKernelGGL(k_wgt, dim3(601 * 7), dim3(256), 0, stream, Wg, bg, Wgbt);
  hipLaunchKernelGGL(k_zero, dim3(1008), dim3(256), 0, stream, Wgbt);
  for (int row0 = 0; row0 < NROWS; row0 += rows_chunk) {
    int rc = NROWS - row0; if (rc > rows_chunk) rc = rows_chunk;
    hipLaunchKernelGGL(k_gemm, dim3((rc / 256) * NTT), dim3(512), 0, stream,
                       Abf + (size_t)row0 * NKP, Wgbt, E, rc / 256);
    hipLaunchKernelGGL(k_mix, dim3(rc * 2), dim3(512), 0, stream, E, x, out, row0);
  }
}

// Round 13
// 213.003 us; speedup vs baseline: 1.0398x; 1.0398x over previous
//
#include <hip/hip_runtime.h>
#include <hip/hip_bf16.h>
#include <stdint.h>
#include <stddef.h>

#define NB    64      // batch
#define NTOK  784
#define DIMC  256
#define NN2   4
#define NM    8
#define NHW   196
#define NWIN  32      // windows per batch
#define NROWS 2048    // NB*NWIN
#define NK    392
#define NKP   448     // K padded (bias at k=392, zeros after)
#define NBIG  38416   // HW*HW source cols
#define NIP   200     // i-stride within a j-row of E
#define STROW 39200   // used elements per window-row of E
#define STROW2 39232  // padded window-row stride
#define NPT   39424   // padded B rows (col')
#define NTT   307     // N tiles of 128
#define PTS   232     // xvT i-stride

typedef __attribute__((ext_vector_type(4))) float f32x4;
typedef __attribute__((ext_vector_type(8))) short bf16x8;

static __device__ __forceinline__ float bf2f(unsigned short u) {
  union { unsigned int i; float f; } v; v.i = ((unsigned int)u) << 16; return v.f;
}
static __device__ __forceinline__ unsigned short f2bf(float f) {
  union { float f; unsigned int i; } v; v.f = f;
  unsigned int r = v.i + 0x7fffu + ((v.i >> 16) & 1u);  // RNE
  return (unsigned short)(r >> 16);
}

// ---------- kernel 1: compress (x@Wc+bc) + rearrange -> A bf16 [NROWS][NKP]
// K-pad: A[.,392] = 1.0 (bias lane), rest 0.
__global__ __launch_bounds__(256) void k_compress(
    const float* __restrict__ x, const float* __restrict__ Wc,
    const float* __restrict__ bc, unsigned short* __restrict__ Abf) {
  __shared__ float wcs[16 * 256];
  __shared__ float bcs[16];
  const int tid = threadIdx.x;
  const int b  = blockIdx.x / NN2;
  const int n2 = blockIdx.x % NN2;
  for (int idx = tid; idx < 4096; idx += 256) {
    int c = idx >> 4, md = idx & 15;
    wcs[md * 256 + c] = Wc[idx];
  }
  if (tid < 16) bcs[tid] = bc[tid];
  __syncthreads();
  if (tid < NHW) {
    const int h = tid / 7, wcol = tid % 7;
    const int t = h * 28 + n2 * 7 + wcol;
    const float* xp = x + ((size_t)b * NTOK + t) * DIMC;
    float acc[16];
    #pragma unroll
    for (int md = 0; md < 16; ++md) acc[md] = bcs[md];
    for (int c = 0; c < 256; c += 4) {
      const f32x4 xv = *(const f32x4*)(xp + c);
      #pragma unroll
      for (int md = 0; md < 16; ++md) {
        const f32x4 wv = *(const f32x4*)(wcs + md * 256 + c);
        acc[md] += xv[0]*wv[0] + xv[1]*wv[1] + xv[2]*wv[2] + xv[3]*wv[3];
      }
    }
    #pragma unroll
    for (int md = 0; md < 16; ++md) {
      const int m = md >> 1, d = md & 1;
      const int r = b * NWIN + n2 * NM + m;
      Abf[(size_t)r * NKP + tid * 2 + d] = f2bf(acc[md]);
    }
  }
  for (int e = tid; e < NM * (NKP - NK); e += 256) {
    const int m = e / (NKP - NK);
    const int k = NK + (e % (NKP - NK));
    const int r = b * NWIN + n2 * NM + m;
    Abf[(size_t)r * NKP + k] = (k == NK) ? (unsigned short)0x3F80 : 0;
  }
}

// ---------- kernel 2: Wg [NK][NBIG] f32 (+bg folded at k=392) -> Wgbt [NPT][NKP] bf16
__global__ __launch_bounds__(256) void k_wgt(
    const float* __restrict__ Wg, const float* __restrict__ bg,
    unsigned short* __restrict__ Wgbt) {
  __shared__ float tile[64][65];
  const int bid = blockIdx.x;
  const int n0 = (bid % 601) * 64;
  const int k0 = (bid / 601) * 64;
  const int tid = threadIdx.x;
  for (int idx = tid; idx < 4096; idx += 256) {
    const int kk = idx >> 6, nn = idx & 63;
    const int k = k0 + kk, n = n0 + nn;
    float v = 0.f;
    if (n < NBIG) {
      if (k < NK) v = Wg[(size_t)k * NBIG + n];
      else if (k == NK) v = bg[n];
    }
    tile[nn][kk] = v;
  }
  __syncthreads();
  for (int idx = tid; idx < 512; idx += 256) {
    const int nn = idx >> 3, gg = idx & 7;
    const int n = n0 + nn;
    if (n < NBIG) {
      const int i = n / NHW, j = n - (n / NHW) * NHW;
      const int np = j * NIP + i;
      unsigned short u8[8];
      #pragma unroll
      for (int e = 0; e < 8; ++e) u8[e] = f2bf(tile[nn][gg * 8 + e]);
      *(uint4*)&Wgbt[(size_t)np * NKP + k0 + gg * 8] = *(const uint4*)u8;
    }
  }
}

// ---------- kernel 2b: zero Wgbt pad rows (i in [196,200) and rows >= 39200)
__global__ __launch_bounds__(256) void k_zero(unsigned short* __restrict__ Wgbt) {
  const int bid = blockIdx.x;
  int np;
  if (bid < 784) { const int j = bid >> 2, i = 196 + (bid & 3); np = j * NIP + i; }
  else           { np = STROW + (bid - 784); }
  unsigned int* p = (unsigned int*)(Wgbt + (size_t)np * NKP);
  if (threadIdx.x < 224) p[threadIdx.x] = 0u;
}

// ---------- kernel 3: E[rc][STROW2] = exp(A @ Wgbt^T)   (bias folded into K)
// R8 128x128 swizzled-dbuf core, but with counted-vmcnt raw barriers:
// next-tile staging loads stay in flight across the barrier (no vmcnt(0) drain).
__global__ __launch_bounds__(256) void k_gemm(
    const unsigned short* __restrict__ A,    // chunk base [rc][NKP]
    const unsigned short* __restrict__ Bt,   // [NPT][NKP]
    unsigned short* __restrict__ E, int mtiles) {
  __shared__ __align__(128) short smem[32768];   // 64 KB
  const int tid = threadIdx.x;
  const int w = tid >> 6, lane = tid & 63;
  const int nwg = gridDim.x;
  const int q = nwg >> 3, rr = nwg & 7;
  const int xcd = blockIdx.x & 7, pos = blockIdx.x >> 3;
  const int wg = (xcd < rr ? xcd * (q + 1) : rr * (q + 1) + (xcd - rr) * q) + pos;
  const int nt = wg / mtiles, mt = wg % mtiles;
  const int m0 = mt * 128, n0 = nt * 128;
  const int wm = (w >> 1) * 64, wn = (w & 1) * 64;
  const int lrow = lane >> 3;
  const int lcolsw = ((lane & 7) ^ lrow) * 8;   // pre-swizzled source granule

  const unsigned short* Arow = A  + (size_t)(m0 + w * 32 + lrow) * NKP + lcolsw;
  const unsigned short* Brow = Bt + (size_t)(n0 + w * 32 + lrow) * NKP + lcolsw;

  auto stage = [&](int kt, int buf) {
    #pragma unroll
    for (int is = 0; is < 4; ++is) {
      const int gg = w * 4 + is;
      __builtin_amdgcn_global_load_lds(
          (const __attribute__((address_space(1))) void*)(Arow + (size_t)is * 8 * NKP + kt),
          (__attribute__((address_space(3))) void*)((char*)smem + buf * 16384 + gg * 1024), 16, 0, 0);
      __builtin_amdgcn_global_load_lds(
          (const __attribute__((address_space(1))) void*)(Brow + (size_t)is * 8 * NKP + kt),
          (__attribute__((address_space(3))) void*)((char*)smem + 32768 + buf * 16384 + gg * 1024), 16, 0, 0);
    }
  };

  f32x4 acc[4][4] = {};
  stage(0, 0);
  const int lq = lane >> 4;
  const int lx = (lane & 7);
  #pragma unroll
  for (int t = 0; t < 7; ++t) {
    const int buf = t & 1;
    if (t < 6) {
      stage((t + 1) * 64, buf ^ 1);
      asm volatile("s_waitcnt vmcnt(8)" ::: "memory");   // tile-t loads (oldest 8) landed
    } else {
      asm volatile("s_waitcnt vmcnt(0)" ::: "memory");
    }
    __builtin_amdgcn_s_barrier();
    __builtin_amdgcn_sched_barrier(0);                   // keep ds_reads below the barrier
    const short* ab = smem + buf * 8192;
    const short* bb = smem + 16384 + buf * 8192;
    #pragma unroll
    for (int kk = 0; kk < 2; ++kk) {
      bf16x8 af[4], bfr[4];
      #pragma unroll
      for (int i = 0; i < 4; ++i) {
        const int row = wm + i * 16 + (lane & 15);
        const int slot = ((kk * 4 + lq) ^ lx) * 8;
        af[i]  = *(const bf16x8*)(ab + row * 64 + slot);
        const int rowb = wn + i * 16 + (lane & 15);
        bfr[i] = *(const bf16x8*)(bb + rowb * 64 + slot);
      }
      #pragma unroll
      for (int mi = 0; mi < 4; ++mi)
        #pragma unroll
        for (int ni = 0; ni < 4; ++ni)
          acc[mi][ni] = __builtin_amdgcn_mfma_f32_16x16x32_bf16(af[mi], bfr[ni], acc[mi][ni], 0, 0, 0);
    }
    __builtin_amdgcn_sched_barrier(0);                   // keep ds_reads above the barrier
    __builtin_amdgcn_s_barrier();
  }

  // epilogue: exp -> LDS (stride 132) -> coalesced 16B stores
  const int cq = lane >> 4, cr = lane & 15;
  #pragma unroll
  for (int mi = 0; mi < 4; ++mi)
    #pragma unroll
    for (int ni = 0; ni < 4; ++ni)
      #pragma unroll
      for (int e = 0; e < 4; ++e) {
        const int rl = wm + mi * 16 + cq * 4 + e;
        const int cl = wn + ni * 16 + cr;
        smem[rl * 132 + cl] = (short)f2bf(__expf(acc[mi][ni][e]));
      }
  __syncthreads();
  for (int idx = tid; idx < 2048; idx += 256) {
    const int rl = idx >> 4, seg = idx & 15;
    const int col0 = n0 + seg * 8;
    if (col0 < STROW2) {
      const uint4 v = *(const uint4*)&smem[rl * 132 + seg * 8];
      *(uint4*)&E[(size_t)(m0 + rl) * STROW2 + col0] = v;
    }
  }
}

// ---------- kernel 4: mix. Window split across 2 blocks at jt granularity.
__global__ __launch_bounds__(512) void k_mix(
    const unsigned short* __restrict__ E, const float* __restrict__ x,
    float* __restrict__ out, int row0) {
  __shared__ unsigned short Elds[22528];     // up to 44 chunks * 64 granules * 8
  __shared__ unsigned short xvT[32 * PTS];   // [c][i] bf16
  const int tid = threadIdx.x, w = tid >> 6, lane = tid & 63;
  const int row = blockIdx.x >> 1, jh = blockIdx.x & 1;
  const int r = row0 + row;
  const int b = r >> 5, win = r & 31, n2 = win >> 3, m = win & 7;

  // phase 1: stream E half-row into LDS (linear), issue first
  const unsigned short* Eb = E + (size_t)row * STROW2;
  const int g0 = jh ? 2800 : 0;            // first 8-short granule of this half
  const int nch = jh ? 33 : 44;            // 64-granule chunks streamed
  for (int ch = w; ch < nch; ch += 8) {
    const int gr = g0 + ch * 64 + lane;
    if (gr < 4904)
      __builtin_amdgcn_global_load_lds(
          (const __attribute__((address_space(1))) void*)(Eb + (size_t)gr * 8),
          (__attribute__((address_space(3))) void*)((char*)Elds + ch * 1024), 16, 0, 0);
  }

  // phase 2: xvT[c][i] = x[b, t(i), m*32+c]; zero pads i in [196,232)
  for (int idx = tid; idx < 1568; idx += 512) {
    const int i = idx >> 3, c4 = (idx & 7) * 4;
    const int t = (i / 7) * 28 + n2 * 7 + (i % 7);
    const f32x4 v = *(const f32x4*)(x + ((size_t)b * NTOK + t) * DIMC + m * 32 + c4);
    xvT[(c4 + 0) * PTS + i] = f2bf(v[0]);
    xvT[(c4 + 1) * PTS + i] = f2bf(v[1]);
    xvT[(c4 + 2) * PTS + i] = f2bf(v[2]);
    xvT[(c4 + 3) * PTS + i] = f2bf(v[3]);
  }
  for (int idx = tid; idx < 32 * (PTS - NHW); idx += 512) {
    const int c = idx / (PTS - NHW), i = NHW + idx % (PTS - NHW);
    xvT[c * PTS + i] = 0;
  }
  __syncthreads();

  // hoist B-frags (channels) + ones-frags for the denominator
  bf16x8 bfr[2][7];
  #pragma unroll
  for (int ct = 0; ct < 2; ++ct)
    #pragma unroll
    for (int kk = 0; kk < 7; ++kk)
      bfr[ct][kk] = *(const bf16x8*)&xvT[(ct * 16 + (lane & 15)) * PTS + kk * 32 + (lane >> 4) * 8];
  const bool den = (lane & 15) == 0;
  bf16x8 oneA, oneB;
  #pragma unroll
  for (int e = 0; e < 8; ++e) {
    oneA[e] = den ? (short)0x3F80 : (short)0;
    const int i6 = 192 + (lane >> 4) * 8 + e;
    oneB[e] = (den && i6 < NHW) ? (short)0x3F80 : (short)0;
  }

  // phase 3: MFMA from LDS; wave w owns jt = jt0 + w
  const int jt0 = jh ? 7 : 0;
  const int jtend = jh ? 13 : 7;
  for (int jt = jt0 + w; jt < jtend; jt += 8) {
    const int jA = jt * 16 + (lane & 15);
    const int jAc = (jA < NHW) ? jA : NHW - 1;
    const unsigned short* rp = Elds + jAc * NIP - jh * 22400 + (lane >> 4) * 8;
    bf16x8 af[7];
    #pragma unroll
    for (int kk = 0; kk < 7; ++kk) af[kk] = *(const bf16x8*)(rp + kk * 32);
    f32x4 a0 = {0.f,0.f,0.f,0.f}, a1 = {0.f,0.f,0.f,0.f}, ad = {0.f,0.f,0.f,0.f};
    #pragma unroll
    for (int kk = 0; kk < 7; ++kk) {
      a0 = __builtin_amdgcn_mfma_f32_16x16x32_bf16(af[kk], bfr[0][kk], a0, 0, 0, 0);
      a1 = __builtin_amdgcn_mfma_f32_16x16x32_bf16(af[kk], bfr[1][kk], a1, 0, 0, 0);
      ad = __builtin_amdgcn_mfma_f32_16x16x32_bf16(af[kk], (kk < 6) ? oneA : oneB, ad, 0, 0, 0);
    }
    const int c = lane & 15;
    #pragma unroll
    for (int e = 0; e < 4; ++e) {
      const int j = jt * 16 + (lane >> 4) * 4 + e;
      const float dv = __shfl(ad[e], lane & 48);
      if (j < NHW) {
        const float inv = 1.f / dv;
        const int t2 = (j / 7) * 28 + n2 * 7 + (j % 7);
        float* op = out + ((size_t)b * NTOK + t2) * DIMC + m * 32;
        op[c] = a0[e] * inv;
        op[c + 16] = a1[e] * inv;
      }
    }
  }
}

extern "C" void kernel_launch(void* const* d_in, const int* in_sizes, int n_in,
                              void* d_out, int out_size, void* d_ws, size_t ws_size,
                              hipStream_t stream) {
  const float* x  = (const float*)d_in[0];
  const float* Wc = (const float*)d_in[1];
  const float* bc = (const float*)d_in[2];
  const float* Wg = (const float*)d_in[3];
  const float* bg = (const float*)d_in[4];
  float* out = (float*)d_out;

  char* ws = (char*)d_ws;
  const size_t wgbt_bytes = (size_t)NPT * NKP * 2;     // 35.3 MB
  const size_t a_bytes    = (size_t)NROWS * NKP * 2;   // 1.8 MB
  unsigned short* Wgbt = (unsigned short*)ws;
  unsigned short* Abf  = (unsigned short*)(ws + wgbt_bytes);
  unsigned short* E    = (unsigned short*)(ws + wgbt_bytes + a_bytes);
  const size_t fixed = wgbt_bytes + a_bytes;
  const size_t srow_bytes = (size_t)STROW2 * 2;        // 78.5 KB per window-row

  size_t avail = (ws_size > fixed) ? (ws_size - fixed) : 0;
  int rows_chunk = (int)(avail / srow_bytes);
  rows_chunk = (rows_chunk / 128) * 128;
  if (rows_chunk > NROWS) rows_chunk = NROWS;
  if (rows_chunk < 128)  rows_chunk = 128;

  hipLaunchKernelGGL(k_compress, dim3(NB * NN2), dim3(256), 0, stream, x, Wc, bc, Abf);
  hipLaunchKernelGGL(k_wgt, dim3(601 * 7), dim3(256), 0, stream, Wg, bg, Wgbt);
  hipLaunchKernelGGL(k_zero, dim3(1008), dim3(256), 0, stream, Wgbt);
  for (int row0 = 0; row0 < NROWS; row0 += rows_chunk) {
    int rc = NROWS - row0; if (rc > rows_chunk) rc = rows_chunk;
    hipLaunchKernelGGL(k_gemm, dim3((rc / 128) * NTT), dim3(256), 0, stream,
                       Abf + (size_t)row0 * NKP, Wgbt, E, rc / 128);
    hipLaunchKernelGGL(k_mix, dim3(rc * 2), dim3(512), 0, stream, E, x, out, row0);
  }
}